// Round 2
// baseline (201.582 us; speedup 1.0000x reference)
//
#include <hip/hip_runtime.h>
#include <math.h>

#define KBINS 128
#define NTHR  256

// ---------------------------------------------------------------------------
// Main pass. 256 thr = 4 waves = 8 half-waves per block; each half-wave
// processes one row per iteration; lane (l32) owns 4 columns via one float4
// load (16 B/lane, coalesced 1 KiB per wave instruction).
// Outputs per block: per-column masked sum-exp partial, per-column event
// histogram partial (pure VALU, no atomics), S1 partial, event-count partial.
// Partials stored TRANSPOSED: part[k * nblk + block] for coalesced fin reads.
// ---------------------------------------------------------------------------
__global__ __launch_bounds__(NTHR) void cox_main(
    const float* __restrict__ logits, const int* __restrict__ labels,
    const int* __restrict__ events, float* __restrict__ part_denom,
    int* __restrict__ part_hist, float* __restrict__ part_s1,
    int* __restrict__ part_ev, int B, int nblk)
{
    __shared__ float dsum[8][KBINS];
    __shared__ int   hsum[8][KBINS];
    __shared__ float s1sh[8];
    __shared__ int   evsh[8];

    const int t    = threadIdx.x;
    const int wave = t >> 6;
    const int lane = t & 63;
    const int half = lane >> 5;       // half-wave id within wave
    const int l32  = lane & 31;
    const int hid  = wave * 2 + half; // 0..7
    const int c0   = l32 << 2;        // first of this lane's 4 columns

    float sa0 = 0.f, sa1 = 0.f, sa2 = 0.f, sa3 = 0.f;
    int   h0 = 0, h1 = 0, h2 = 0, h3 = 0;
    float accOwn = 0.f;
    int   accEv  = 0;

    const float4* __restrict__ lg4 = reinterpret_cast<const float4*>(logits);
    const int rowsPerIter = nblk * 8;

    #pragma unroll 2
    for (int r = blockIdx.x * 8 + hid; r < B; r += rowsPerIter) {
        const float4 v  = lg4[(size_t)r * (KBINS / 4) + l32];
        const int   lab = labels[r];
        const int   ev  = events[r];
        const float e0 = __expf(v.x);
        const float e1 = __expf(v.y);
        const float e2 = __expf(v.z);
        const float e3 = __expf(v.w);
        if (lab >= c0    ) sa0 += e0;
        if (lab >= c0 + 1) sa1 += e1;
        if (lab >= c0 + 2) sa2 += e2;
        if (lab >= c0 + 3) sa3 += e3;
        if (ev) {
            if      (lab == c0    ) { accOwn += v.x; h0++; }
            else if (lab == c0 + 1) { accOwn += v.y; h1++; }
            else if (lab == c0 + 2) { accOwn += v.z; h2++; }
            else if (lab == c0 + 3) { accOwn += v.w; h3++; }
            if (l32 == 0) accEv++;   // one count per row
        }
    }

    // columns are disjoint per lane within a half-wave: direct LDS store
    dsum[hid][c0    ] = sa0;  hsum[hid][c0    ] = h0;
    dsum[hid][c0 + 1] = sa1;  hsum[hid][c0 + 1] = h1;
    dsum[hid][c0 + 2] = sa2;  hsum[hid][c0 + 2] = h2;
    dsum[hid][c0 + 3] = sa3;  hsum[hid][c0 + 3] = h3;

    // reduce accOwn across the 32 lanes of the half-wave
    for (int off = 16; off; off >>= 1)
        accOwn += __shfl_down(accOwn, off, 32);
    if (l32 == 0) { s1sh[hid] = accOwn; evsh[hid] = accEv; }
    __syncthreads();

    if (t < KBINS) {
        float d = 0.f; int h = 0;
        #pragma unroll
        for (int i = 0; i < 8; ++i) { d += dsum[i][t]; h += hsum[i][t]; }
        const size_t o = (size_t)t * nblk + blockIdx.x;   // transposed
        part_denom[o] = d;
        part_hist[o]  = h;
    }
    if (t == 0) {
        float s1 = 0.f; int e = 0;
        #pragma unroll
        for (int i = 0; i < 8; ++i) { s1 += s1sh[i]; e += evsh[i]; }
        part_s1[blockIdx.x] = s1;
        part_ev[blockIdx.x] = e;
    }
}

// ---------------------------------------------------------------------------
// Blocks 0..127: term[k] = n_ev[k]>0 ? n_ev[k]*log(denom[k]) : 0 (coalesced
// reads of the transposed partials). Block 128: reduce S1 and event count.
// ---------------------------------------------------------------------------
__global__ __launch_bounds__(256) void cox_fin1(
    const float* __restrict__ part_denom, const int* __restrict__ part_hist,
    const float* __restrict__ part_s1, const int* __restrict__ part_ev,
    double* __restrict__ term, int nblk)
{
    const int k = blockIdx.x;
    const int t = threadIdx.x;
    __shared__ double ds[256];
    __shared__ long   hs[256];

    double d = 0.0;
    long   h = 0;
    if (k < KBINS) {
        const float* pd = part_denom + (size_t)k * nblk;
        const int*   ph = part_hist  + (size_t)k * nblk;
        for (int b = t; b < nblk; b += 256) { d += (double)pd[b]; h += ph[b]; }
    } else {
        for (int b = t; b < nblk; b += 256) { d += (double)part_s1[b]; h += part_ev[b]; }
    }
    ds[t] = d; hs[t] = h;
    __syncthreads();
    for (int off = 128; off; off >>= 1) {
        if (t < off) { ds[t] += ds[t + off]; hs[t] += hs[t + off]; }
        __syncthreads();
    }
    if (t == 0) {
        if (k < KBINS) term[k] = (hs[0] > 0) ? (double)hs[0] * log(ds[0]) : 0.0;
        else { term[KBINS] = ds[0]; term[KBINS + 1] = (double)hs[0]; }
    }
}

// ---------------------------------------------------------------------------
// Single tiny block: loss = (sum_k term[k] - S1) / max(n_events, 1)
// ---------------------------------------------------------------------------
__global__ __launch_bounds__(128) void cox_fin2(
    const double* __restrict__ term, float* __restrict__ out)
{
    const int t = threadIdx.x;
    double v = term[t];
    for (int off = 32; off; off >>= 1)
        v += __shfl_down(v, off, 64);
    __shared__ double w[2];
    if ((t & 63) == 0) w[t >> 6] = v;
    __syncthreads();
    if (t == 0) {
        const double s2   = w[0] + w[1];
        const double s1   = term[KBINS];
        const double ne   = term[KBINS + 1];
        const double ntot = ne > 1.0 ? ne : 1.0;
        out[0] = (float)((s2 - s1) / ntot);
    }
}

// ---------------------------------------------------------------------------
extern "C" void kernel_launch(void* const* d_in, const int* in_sizes, int n_in,
                              void* d_out, int out_size, void* d_ws, size_t ws_size,
                              hipStream_t stream) {
    const float* logits = (const float*)d_in[0];
    const int*   labels = (const int*)d_in[1];
    const int*   events = (const int*)d_in[2];
    const int B = in_sizes[1];

    int nblk = 2048;
    auto need = [](size_t nb) {
        return nb * KBINS * 4 * 2        // part_denom + part_hist
             + nb * 8                    // part_s1 + part_ev
             + (KBINS + 2) * 8 + 64;     // term (double)
    };
    while (nblk > 64 && need((size_t)nblk) > ws_size) nblk >>= 1;

    char* ws = (char*)d_ws;
    float*  part_denom = (float*)ws;
    int*    part_hist  = (int*)(ws + (size_t)nblk * KBINS * 4);
    float*  part_s1    = (float*)(ws + (size_t)2 * nblk * KBINS * 4);
    int*    part_ev    = (int*)(ws + (size_t)2 * nblk * KBINS * 4 + (size_t)nblk * 4);
    double* term       = (double*)(ws + (size_t)2 * nblk * KBINS * 4 + (size_t)2 * nblk * 4);

    cox_main<<<nblk, NTHR, 0, stream>>>(logits, labels, events,
                                        part_denom, part_hist, part_s1, part_ev,
                                        B, nblk);
    cox_fin1<<<KBINS + 1, 256, 0, stream>>>(part_denom, part_hist,
                                            part_s1, part_ev, term, nblk);
    cox_fin2<<<1, 128, 0, stream>>>(term, (float*)d_out);
}